// Round 12
// baseline (182.473 us; speedup 1.0000x reference)
//
#include <hip/hip_runtime.h>
#include <stdint.h>
#include <math.h>

#define NH 32
#define NH2 8
#define DD 128
#define KSEL 128
#define GG 4
#define S2MASK 8191   // S2=8192

__global__ __launch_bounds__(256) void sparse_attn_kernel(
    const float* __restrict__ q, const float* __restrict__ k,
    const float* __restrict__ v, const int* __restrict__ idx,
    float* __restrict__ out) {
  __shared__ int sIdx[4][KSEL];
  __shared__ __align__(16) float sS[4][GG][KSEL];
  __shared__ __align__(16) float sP[4][KSEL][GG];

  const int tid = threadIdx.x;
  const int w = tid >> 6;      // wave slot in block
  const int lane = tid & 63;
  const int h2 = blockIdx.x & 7;                 // XCD-pinned KV head
  const int s1 = ((blockIdx.x >> 3) << 2) + w;   // query position

  // ---- sparse indices for this (s1,h2) ----
  const int* ip = idx + (s1 * NH2 + h2) * KSEL;
  sIdx[w][lane]      = ip[lane] & S2MASK;
  sIdx[w][lane + 64] = ip[lane + 64] & S2MASK;

  // ---- Q group into registers: lane chunk c covers d=[8c,8c+8) ----
  const int c = lane & 15;   // d-chunk
  const int r = lane >> 4;   // row slot (4 K-rows in flight per wave)
  float4 qa[GG], qb[GG];
  const float* qp = q + (s1 * NH + h2 * GG) * DD + c * 8;
#pragma unroll
  for (int g = 0; g < GG; ++g) {
    qa[g] = *(const float4*)(qp + g * DD);
    qb[g] = *(const float4*)(qp + g * DD + 4);
  }

  __syncthreads();

  const float scale = 0.08838834764831845f;  // 1/sqrt(128)

  // ---- Phase 1: scores = Q . K_gathered ----
#pragma unroll 4
  for (int it = 0; it < 32; ++it) {
    const int j = it * 4 + r;
    const int s2 = sIdx[w][j];
    const float* kp = k + (s2 * NH2 + h2) * DD + c * 8;
    const float4 ka = *(const float4*)(kp);
    const float4 kb = *(const float4*)(kp + 4);
    float sg0, sg1, sg2, sg3;
    {
      sg0 = qa[0].x * ka.x; sg1 = qa[1].x * ka.x;
      sg2 = qa[2].x * ka.x; sg3 = qa[3].x * ka.x;
      sg0 = fmaf(qa[0].y, ka.y, sg0); sg1 = fmaf(qa[1].y, ka.y, sg1);
      sg2 = fmaf(qa[2].y, ka.y, sg2); sg3 = fmaf(qa[3].y, ka.y, sg3);
      sg0 = fmaf(qa[0].z, ka.z, sg0); sg1 = fmaf(qa[1].z, ka.z, sg1);
      sg2 = fmaf(qa[2].z, ka.z, sg2); sg3 = fmaf(qa[3].z, ka.z, sg3);
      sg0 = fmaf(qa[0].w, ka.w, sg0); sg1 = fmaf(qa[1].w, ka.w, sg1);
      sg2 = fmaf(qa[2].w, ka.w, sg2); sg3 = fmaf(qa[3].w, ka.w, sg3);
      sg0 = fmaf(qb[0].x, kb.x, sg0); sg1 = fmaf(qb[1].x, kb.x, sg1);
      sg2 = fmaf(qb[2].x, kb.x, sg2); sg3 = fmaf(qb[3].x, kb.x, sg3);
      sg0 = fmaf(qb[0].y, kb.y, sg0); sg1 = fmaf(qb[1].y, kb.y, sg1);
      sg2 = fmaf(qb[2].y, kb.y, sg2); sg3 = fmaf(qb[3].y, kb.y, sg3);
      sg0 = fmaf(qb[0].z, kb.z, sg0); sg1 = fmaf(qb[1].z, kb.z, sg1);
      sg2 = fmaf(qb[2].z, kb.z, sg2); sg3 = fmaf(qb[3].z, kb.z, sg3);
      sg0 = fmaf(qb[0].w, kb.w, sg0); sg1 = fmaf(qb[1].w, kb.w, sg1);
      sg2 = fmaf(qb[2].w, kb.w, sg2); sg3 = fmaf(qb[3].w, kb.w, sg3);
    }
#pragma unroll
    for (int off = 1; off < 16; off <<= 1) {
      sg0 += __shfl_xor(sg0, off);
      sg1 += __shfl_xor(sg1, off);
      sg2 += __shfl_xor(sg2, off);
      sg3 += __shfl_xor(sg3, off);
    }
    float val = (c == 0) ? sg0 : (c == 1) ? sg1 : (c == 2) ? sg2 : sg3;
    if (c < GG) sS[w][c][j] = val * scale;
  }
  __syncthreads();

  // ---- Phase 2: softmax per head (K=128 values, 2 per lane) ----
#pragma unroll
  for (int g = 0; g < GG; ++g) {
    float a0 = sS[w][g][lane];
    float a1 = sS[w][g][lane + 64];
    float m = fmaxf(a0, a1);
#pragma unroll
    for (int off = 32; off >= 1; off >>= 1) m = fmaxf(m, __shfl_xor(m, off));
    float e0 = expf(a0 - m);
    float e1 = expf(a1 - m);
    float s = e0 + e1;
#pragma unroll
    for (int off = 32; off >= 1; off >>= 1) s += __shfl_xor(s, off);
    const float inv = 1.0f / fmaxf(s, 1e-30f);
    sP[w][lane][g]      = e0 * inv;
    sP[w][lane + 64][g] = e1 * inv;
  }
  __syncthreads();

  // ---- Phase 3: O = P . V_gathered ; lane owns d-pair d=2*lane ----
  float a00 = 0.f, a01 = 0.f, a10 = 0.f, a11 = 0.f;
  float a20 = 0.f, a21 = 0.f, a30 = 0.f, a31 = 0.f;
  const float* vb = v + h2 * DD + lane * 2;
#pragma unroll 8
  for (int j = 0; j < KSEL; ++j) {
    const int s2 = sIdx[w][j];
    const float2 vv = *(const float2*)(vb + (size_t)s2 * (NH2 * DD));
    const float4 p = *(const float4*)&sP[w][j][0];
    a00 = fmaf(p.x, vv.x, a00); a01 = fmaf(p.x, vv.y, a01);
    a10 = fmaf(p.y, vv.x, a10); a11 = fmaf(p.y, vv.y, a11);
    a20 = fmaf(p.z, vv.x, a20); a21 = fmaf(p.z, vv.y, a21);
    a30 = fmaf(p.w, vv.x, a30); a31 = fmaf(p.w, vv.y, a31);
  }

  // ---- output: float32 buffer, np.float32 readback ----
  float* op = out + (s1 * NH + h2 * GG) * DD + lane * 2;
  *(float2*)(op + 0 * DD) = make_float2(a00, a01);
  *(float2*)(op + 1 * DD) = make_float2(a10, a11);
  *(float2*)(op + 2 * DD) = make_float2(a20, a21);
  *(float2*)(op + 3 * DD) = make_float2(a30, a31);
}

extern "C" void kernel_launch(void* const* d_in, const int* in_sizes, int n_in,
                              void* d_out, int out_size, void* d_ws, size_t ws_size,
                              hipStream_t stream) {
  // World (measured, R11 probe + R10/R4/R5 quantitative fits):
  //   inputs = float32 (harness upcasts fp16), positional order q,k,v,idx;
  //   in_sizes = element counts; idx = int32 in [0,8192);
  //   output = float32 buffer, np.float32 readback.
  const float* q = (const float*)d_in[0];
  const float* k = (const float*)d_in[1];
  const float* v = (const float*)d_in[2];
  const int* idx = (const int*)d_in[3];
  float* out = (float*)d_out;
  sparse_attn_kernel<<<dim3(2048), dim3(256), 0, stream>>>(q, k, v, idx, out);
}